// Round 16
// baseline (1798.217 us; speedup 1.0000x reference)
//
#include <hip/hip_runtime.h>

#define BATCH    1024
#define UNITS    1024
#define INSTEPS  64
#define OUTSTEPS 32
#define NF       4
#define NSTEPS   (INSTEPS + OUTSTEPS - 1)   // 95

typedef _Float16 half8 __attribute__((ext_vector_type(8)));
typedef float    f32x4 __attribute__((ext_vector_type(4)));

__device__ __forceinline__ float sigf(float x)  { return 1.0f / (1.0f + __expf(-x)); }
__device__ __forceinline__ float tanhf_(float x){ return 1.0f - 2.0f / (__expf(2.0f * x) + 1.0f); }

// 16-lane row sum via DPP row_shr (VALU pipe, no LDS ops). Result in lane 15
// of each 16-lane row (bound_ctrl=1 -> shifted-in lanes contribute 0).
__device__ __forceinline__ float dpp_rowsum16(float v) {
    int x;
    x = __builtin_amdgcn_update_dpp(0, __builtin_bit_cast(int, v), 0x111, 0xf, 0xf, true);
    v += __builtin_bit_cast(float, x);   // += row_shr:1
    x = __builtin_amdgcn_update_dpp(0, __builtin_bit_cast(int, v), 0x112, 0xf, 0xf, true);
    v += __builtin_bit_cast(float, x);   // += row_shr:2
    x = __builtin_amdgcn_update_dpp(0, __builtin_bit_cast(int, v), 0x114, 0xf, 0xf, true);
    v += __builtin_bit_cast(float, x);   // += row_shr:4
    x = __builtin_amdgcn_update_dpp(0, __builtin_bit_cast(int, v), 0x118, 0xf, 0xf, true);
    v += __builtin_bit_cast(float, x);   // += row_shr:8
    return v;
}

// One-time: U fp32 [1024 k][4096 n] -> Ut f16 [4096 n][1024 k] (transposed)
__global__ void u_transpose(const float* __restrict__ U, _Float16* __restrict__ Ut) {
    __shared__ _Float16 T[64][72];
    const int tid = threadIdx.x;
    const int bid = blockIdx.x;            // 1024 blocks = 16 (k) x 64 (n)
    const int k0 = (bid >> 6) << 6;
    const int n0 = (bid & 63) << 6;
    #pragma unroll
    for (int i = 0; i < 16; ++i) {
        int q = i * 256 + tid;
        int r = q >> 6, cc = q & 63;
        T[r][cc] = (_Float16)U[(size_t)(k0 + r) * 4096 + n0 + cc];
    }
    __syncthreads();
    #pragma unroll
    for (int i = 0; i < 16; ++i) {
        int q = i * 256 + tid;
        int nn = q >> 6, kk = q & 63;
        Ut[(size_t)(n0 + nn) * 1024 + k0 + kk] = T[kk][nn];
    }
}

// Persistent cooperative kernel, all 95 steps. 256 blocks (1/CU) x 1024 threads.
// R11/R15 skeleton (proven 1776-1782us): K-split 16 waves = 8 row-tiles x 2
// K-halves, 4 waves/SIMD, band counter barrier + agent fence, decode folding
// (U' = U + Wd@W at p==64), transposed h layout + LDS-staged coalesced agent
// h-stores, DPP pred reduce after barrier-arrive, 3-round/6-sync exchange,
// staging syncs only at p==0 / p==INSTEPS.
// R16 delta (isolated, zero-risk hint): s_setprio(1) around the 8-chunk MFMA
// loop, setprio(0) for exchange/epilogue. With 4 waves/SIMD drifting phases
// between syncs (some in MFMA, some in B-read/exchange/VALU), the CU
// scheduler can favor matrix-issuing waves (catalog T5: helps iff role
// diversity exists; null would confirm lockstep and close the last lever).
#define BS_BYTES  (16*64*64*2)                 // 131072
#define XS_BYTES  (256*4*4)                    // 4096
#define SH_OFF    (BS_BYTES + XS_BYTES)
#define SH_BYTES  (3*8*64*16)                  // 24576: xb[3][8][64] f32x4,
                                               // hst[256][18] f16 (9216B) overlaid
#define LDS_BYTES (SH_OFF + SH_BYTES)          // 159744 <= 163840

__global__ __launch_bounds__(1024, 4) void lstm_seq(
    const float* __restrict__ x, const float* __restrict__ W,
    const float* __restrict__ bias, const float* __restrict__ Wd,
    const float* __restrict__ bd, const _Float16* __restrict__ Ut,
    _Float16* hA, _Float16* hB, float* out, unsigned* bar)
{
    extern __shared__ __align__(16) char smem[];
    _Float16 (*Bs)[64][64] = (_Float16 (*)[64][64])smem;       // [16 chunks][64 n][64 k]
    float (*xs)[NF] = (float (*)[NF])(smem + BS_BYTES);        // [256][4]
    f32x4 (*xb)[8][64] = (f32x4 (*)[8][64])(smem + SH_OFF);    // [3][8][64]
    _Float16 (*hst)[18] = (_Float16 (*)[18])(smem + SH_OFF);   // overlaid (xb dead)

    const int tid  = threadIdx.x;
    const int bid  = blockIdx.x;
    const int band = bid & 3;
    const int m0   = band << 8;            // 256-row band, XCD-pair local
    const int u0   = (bid >> 2) << 4;      // 64 u-tiles of 16 units

    const int lane = tid & 63;
    const int wv   = tid >> 6;             // 0..15
    const int rt2  = wv & 7;               // row-tile: rows rt2*32..+31
    const int kh   = wv >> 3;              // K-half: 0 => K[0,512), 1 => K[512,1024)
    const int quad = lane >> 4;
    const int ln   = lane & 15;

    unsigned* cnt = bar + band * 64;       // per-band counter, 256B apart

    // staging geometry (init stage AND the p==64 U' restage) -- first 512 thr
    const int r_st = (tid >> 3) & 63;              // 0..63 (B-col within tile)
    const int ck   = tid & 7;                      // logical 16B chunk
    const int swz  = ((ck ^ (r_st & 7)) << 3);     // physical half-offset
    const int n_st = ((r_st >> 4) << 10) + u0 + (r_st & 15);   // global gate-col
    const _Float16* bsrc = Ut + (size_t)n_st * UNITS + ck * 8;

    // ---- stage B-tile (U) into LDS once, XOR-swizzled on 16B chunks ----
    if (tid < 512) {
        #pragma unroll
        for (int kc = 0; kc < 16; ++kc)
            *(float4*)&Bs[kc][r_st][swz] = *(const float4*)(bsrc + kc * 64);
    }

    // ---- hoisted weights ----
    float wt[4][4], bt[4], btp[4];
    #pragma unroll
    for (int g = 0; g < 4; ++g) {
        int col = (g << 10) + u0 + ln;
        bt[g] = bias[col];
        #pragma unroll
        for (int f = 0; f < 4; ++f) wt[g][f] = W[f * 4096 + col];
    }
    {   // decode bias b' = b + bd@W
        float bdr0 = bd[0], bdr1 = bd[1], bdr2 = bd[2], bdr3 = bd[3];
        #pragma unroll
        for (int g = 0; g < 4; ++g)
            btp[g] = bt[g] + bdr0*wt[g][0] + bdr1*wt[g][1] + bdr2*wt[g][2] + bdr3*wt[g][3];
    }
    const float* wdp = Wd + (size_t)(u0 + ln) * NF;
    float wd0 = wdp[0], wd1 = wdp[1], wd2 = wdp[2], wd3 = wdp[3];
    float bd0 = 0, bd1 = 0, bd2 = 0, bd3 = 0;
    if (u0 == 0) { bd0 = bd[0]; bd1 = bd[1]; bd2 = bd[2]; bd3 = bd[3]; }

    float cr[2][4] = {{0,0,0,0},{0,0,0,0}};   // c-state (kh=0 waves only used)
    float hnv[2][4];                          // h of this step (post-arrive pred)

    // swizzled B-frag read offsets (row&7 == ln&7 for all four row groups)
    const int swz0 = ((quad ^ (ln & 7)) << 3);   // k-sub 0
    const int swz1 = swz0 ^ 32;                  // k-sub 1 (chunk 4+quad)

    // A-load geometry in transposed h layout: addr(row, k) =
    //   (k>>4)*32768 + row*32 + (k&15)*2.  k = kh*512 + kcg*64 + quad*8 + j*32.
    const int row0 = m0 + rt2 * 32 + ln;
    const int aoff = ((quad >> 1) << 15) + row0 * 32 + ((quad & 1) << 4);

    // xt staging: 1024 threads cover 256 rows x 4 features exactly
    const int xr = tid >> 2, xf = tid & 3;
    float xp0 = x[(size_t)(m0 + xr) * (INSTEPS * NF) + xf];

    // coalesced h-store geometry (threads 0..511, wave-private hst rows)
    char* const hAc = (char*)hA;
    char* const hBc = (char*)hB;
    const size_t stoff = ((size_t)(u0 >> 4) << 15) + (size_t)(m0 + (tid >> 1)) * 32
                       + ((size_t)(tid & 1) << 4);

    __syncthreads();   // Bs ready

    for (int p = 0; p < NSTEPS; ++p) {
        if (p < INSTEPS) {                 // warmup: stage xt (ordering for the
            xs[xr][xf] = xp0;              //  epilogue comes from exchange syncs)
        } else if (p == INSTEPS && tid < 512) {
            // ---- re-stage Bs as U' = U + Wd@W (decode folding) ----
            float wc0 = W[n_st], wc1 = W[4096 + n_st],
                  wc2 = W[8192 + n_st], wc3 = W[12288 + n_st];
            #pragma unroll
            for (int kc = 0; kc < 16; ++kc) {
                int k0 = kc * 64 + ck * 8;
                half8 uv = *(const half8*)(bsrc + kc * 64);
                half8 tv;
                #pragma unroll
                for (int j = 0; j < 8; ++j) {
                    const float* wdr = Wd + (size_t)(k0 + j) * NF;
                    float corr = wdr[0]*wc0 + wdr[1]*wc1 + wdr[2]*wc2 + wdr[3]*wc3;
                    tv[j] = (_Float16)((float)uv[j] + corr);
                }
                *(half8*)&Bs[kc][r_st][swz] = tv;
            }
        }
        if (p == 0 || p == INSTEPS) __syncthreads();   // xs(p0)/Bs restage ready

        f32x4 acc[2][4] = {};

        if (p > 0) {
            const char* hb = ((p & 1) ? hAc : hBc) + aoff;   // written at step p-1
#define AL(kcg, j, rr) (*(const half8*)(hb + ((((kcg) << 2) + ((j) << 1)) << 15) + ((rr) << 9)))

            half8 ar[2][4];
            #pragma unroll
            for (int d = 0; d < 2; ++d) {              // depth-2 prefetch pipeline
                const int kcg = (kh << 3) + d;
                ar[d][0] = AL(kcg, 0, 0);
                ar[d][1] = AL(kcg, 1, 0);
                ar[d][2] = AL(kcg, 0, 1);
                ar[d][3] = AL(kcg, 1, 1);
            }

            __builtin_amdgcn_s_setprio(1);             // favor MFMA-issuing waves
            #pragma unroll
            for (int kc = 0; kc < 8; ++kc) {           // my K-half: 8 chunks
                const int sl = kc & 1;
                half8 af0 = ar[sl][0], ag0 = ar[sl][1], af1 = ar[sl][2], ag1 = ar[sl][3];
                if (kc < 6) {
                    const int kcg = (kh << 3) + kc + 2;
                    ar[sl][0] = AL(kcg, 0, 0);
                    ar[sl][1] = AL(kcg, 1, 0);
                    ar[sl][2] = AL(kcg, 0, 1);
                    ar[sl][3] = AL(kcg, 1, 1);
                }
                const _Float16 (*B)[64] = Bs[(kh << 3) + kc];
                half8 bf0 = *(const half8*)&B[ln][swz0];
                half8 bf1 = *(const half8*)&B[16 + ln][swz0];
                half8 bf2 = *(const half8*)&B[32 + ln][swz0];
                half8 bf3 = *(const half8*)&B[48 + ln][swz0];
                acc[0][0] = __builtin_amdgcn_mfma_f32_16x16x32_f16(af0, bf0, acc[0][0], 0, 0, 0);
                acc[1][0] = __builtin_amdgcn_mfma_f32_16x16x32_f16(af1, bf0, acc[1][0], 0, 0, 0);
                acc[0][1] = __builtin_amdgcn_mfma_f32_16x16x32_f16(af0, bf1, acc[0][1], 0, 0, 0);
                acc[1][1] = __builtin_amdgcn_mfma_f32_16x16x32_f16(af1, bf1, acc[1][1], 0, 0, 0);
                acc[0][2] = __builtin_amdgcn_mfma_f32_16x16x32_f16(af0, bf2, acc[0][2], 0, 0, 0);
                acc[1][2] = __builtin_amdgcn_mfma_f32_16x16x32_f16(af1, bf2, acc[1][2], 0, 0, 0);
                acc[0][3] = __builtin_amdgcn_mfma_f32_16x16x32_f16(af0, bf3, acc[0][3], 0, 0, 0);
                acc[1][3] = __builtin_amdgcn_mfma_f32_16x16x32_f16(af1, bf3, acc[1][3], 0, 0, 0);
                half8 bg0 = *(const half8*)&B[ln][swz1];
                half8 bg1 = *(const half8*)&B[16 + ln][swz1];
                half8 bg2 = *(const half8*)&B[32 + ln][swz1];
                half8 bg3 = *(const half8*)&B[48 + ln][swz1];
                acc[0][0] = __builtin_amdgcn_mfma_f32_16x16x32_f16(ag0, bg0, acc[0][0], 0, 0, 0);
                acc[1][0] = __builtin_amdgcn_mfma_f32_16x16x32_f16(ag1, bg0, acc[1][0], 0, 0, 0);
                acc[0][1] = __builtin_amdgcn_mfma_f32_16x16x32_f16(ag0, bg1, acc[0][1], 0, 0, 0);
                acc[1][1] = __builtin_amdgcn_mfma_f32_16x16x32_f16(ag1, bg1, acc[1][1], 0, 0, 0);
                acc[0][2] = __builtin_amdgcn_mfma_f32_16x16x32_f16(ag0, bg2, acc[0][2], 0, 0, 0);
                acc[1][2] = __builtin_amdgcn_mfma_f32_16x16x32_f16(ag1, bg2, acc[1][2], 0, 0, 0);
                acc[0][3] = __builtin_amdgcn_mfma_f32_16x16x32_f16(ag0, bg3, acc[0][3], 0, 0, 0);
                acc[1][3] = __builtin_amdgcn_mfma_f32_16x16x32_f16(ag1, bg3, acc[1][3], 0, 0, 0);
            }
            __builtin_amdgcn_s_setprio(0);
#undef AL

            // ---- partial-z exchange: 3 rounds (3,3,2 pairs), kh=1 writes ----
            #pragma unroll
            for (int rd = 0; rd < 3; ++rd) {
                const int base = rd * 3;
                const int cntw = (rd == 2) ? 2 : 3;
                const int slx  = rt2 - base;
                if (kh == 1 && slx >= 0 && slx < cntw) {
                    #pragma unroll
                    for (int j = 0; j < 8; ++j)
                        xb[slx][j][lane] = acc[j >> 2][j & 3];
                }
                __syncthreads();
                if (kh == 0 && slx >= 0 && slx < cntw) {
                    #pragma unroll
                    for (int j = 0; j < 8; ++j)
                        acc[j >> 2][j & 3] += xb[slx][j][lane];
                }
                __syncthreads();
            }
        }

        const int s_out = p - (INSTEPS - 1);

        if (kh == 0) {
            // ---- epilogue: gates, c/h update into wave-private LDS staging ----
            #pragma unroll
            for (int r = 0; r < 2; ++r) {
                #pragma unroll
                for (int i = 0; i < 4; ++i) {
                    int rl = rt2 * 32 + r * 16 + quad * 4 + i;  // C/D: row=quad*4+reg
                    float zi, zf, zg, zo;
                    if (p < INSTEPS) {
                        float x0 = xs[rl][0], x1 = xs[rl][1], x2 = xs[rl][2], x3 = xs[rl][3];
                        zi = acc[r][0][i] + bt[0] + x0*wt[0][0] + x1*wt[0][1] + x2*wt[0][2] + x3*wt[0][3];
                        zf = acc[r][1][i] + bt[1] + x0*wt[1][0] + x1*wt[1][1] + x2*wt[1][2] + x3*wt[1][3];
                        zg = acc[r][2][i] + bt[2] + x0*wt[2][0] + x1*wt[2][1] + x2*wt[2][2] + x3*wt[2][3];
                        zo = acc[r][3][i] + bt[3] + x0*wt[3][0] + x1*wt[3][1] + x2*wt[3][2] + x3*wt[3][3];
                    } else {                    // decode: x-term folded into U', b'
                        zi = acc[r][0][i] + btp[0];
                        zf = acc[r][1][i] + btp[1];
                        zg = acc[r][2][i] + btp[2];
                        zo = acc[r][3][i] + btp[3];
                    }
                    float cold = cr[r][i];
                    float si = sigf(zi), sf = sigf(zf), so = sigf(zo);
                    float cn = sf * cold + si * tanhf_(zg);
                    float hn = so * tanhf_(cn);
                    cr[r][i] = cn;
                    hnv[r][i] = hn;
                    hst[rl][ln] = (_Float16)hn;            // wave-private staging rows
                }
            }

            // ---- coalesced agent h-store (wave-private hst rows, tid<512) ----
            {
                char* hw = (p & 1) ? hBc : hAc;
                const unsigned long long* sp = (const unsigned long long*)
                    ((const char*)hst + (tid >> 1) * 36 + ((tid & 1) << 4));
                unsigned long long v0 = sp[0], v1 = sp[1];
                unsigned long long* dst = (unsigned long long*)(hw + stoff);
                __hip_atomic_store(dst,     v0, __ATOMIC_RELAXED, __HIP_MEMORY_SCOPE_AGENT);
                __hip_atomic_store(dst + 1, v1, __ATOMIC_RELAXED, __HIP_MEMORY_SCOPE_AGENT);
            }
        }

        const int pn = p + 1;

        // ---- drain h stores, arrive at band barrier ----
        __syncthreads();                               // vmcnt(0): h stores at LLC
        if (tid == 0)
            __hip_atomic_fetch_add(cnt, 1u, __ATOMIC_RELAXED, __HIP_MEMORY_SCOPE_AGENT);

        // ---- pred DPP reduce + out atomics AFTER arrive (overlap the poll) ----
        if (kh == 0 && s_out >= 0) {
            #pragma unroll
            for (int r = 0; r < 2; ++r) {
                #pragma unroll
                for (int i = 0; i < 4; ++i) {
                    float hn = hnv[r][i];
                    float p0 = dpp_rowsum16(hn * wd0);   // VALU-pipe reductions
                    float p1 = dpp_rowsum16(hn * wd1);
                    float p2 = dpp_rowsum16(hn * wd2);
                    float p3 = dpp_rowsum16(hn * wd3);
                    if (ln == 15) {                      // lane 15 holds row sum
                        int R = m0 + rt2 * 32 + r * 16 + quad * 4 + i;
                        float* op = out + (size_t)R * (OUTSTEPS * NF) + s_out * NF;
                        atomicAdd(op + 0, p0 + bd0);
                        atomicAdd(op + 1, p1 + bd1);
                        atomicAdd(op + 2, p2 + bd2);
                        atomicAdd(op + 3, p3 + bd3);
                    }
                }
            }
        }

        if (pn < INSTEPS) {                        // prefetch next xt (warmup only)
            xp0 = x[(size_t)(m0 + xr) * (INSTEPS * NF) + pn * NF + xf];
        }

        // ---- band-local barrier poll (64 blocks on XCD pair {band, band+4}) ----
        if (tid == 0) {
            const unsigned tgt = (unsigned)pn * 64u;
            while (__hip_atomic_load(cnt, __ATOMIC_RELAXED, __HIP_MEMORY_SCOPE_AGENT) < tgt)
                __builtin_amdgcn_s_sleep(1);
            __builtin_amdgcn_fence(__ATOMIC_ACQUIRE, "agent");   // L1/L2 inv
        }
        __syncthreads();                           // also drains out atomics
    }
}

extern "C" void kernel_launch(void* const* d_in, const int* in_sizes, int n_in,
                              void* d_out, int out_size, void* d_ws, size_t ws_size,
                              hipStream_t stream) {
    (void)in_sizes; (void)n_in; (void)ws_size;
    const float* x  = (const float*)d_in[0];
    const float* W  = (const float*)d_in[1];
    const float* U  = (const float*)d_in[2];
    const float* b  = (const float*)d_in[3];
    const float* Wd = (const float*)d_in[4];
    const float* bd = (const float*)d_in[5];
    float* out = (float*)d_out;

    char* ws = (char*)d_ws;
    _Float16* hA  = (_Float16*)ws;                    // 2 MB  h ping   [ut][row][16]
    _Float16* hB  = (_Float16*)(ws + (2 << 20));      // 2 MB  h pong
    _Float16* Ut  = (_Float16*)(ws + (4 << 20));      // 8 MB  U^T f16
    unsigned* bar = (unsigned*)(ws + (12 << 20));     // 4 KB  barrier state

    hipMemsetAsync(bar, 0, 4096, stream);                               // band counters
    hipMemsetAsync(d_out, 0, (size_t)out_size * sizeof(float), stream); // preds accumulate
    u_transpose<<<1024, 256, 0, stream>>>(U, Ut);

    hipFuncSetAttribute((const void*)lstm_seq,
                        hipFuncAttributeMaxDynamicSharedMemorySize, LDS_BYTES);

    void* args[] = {(void*)&x, (void*)&W, (void*)&b, (void*)&Wd, (void*)&bd,
                    (void*)&Ut, (void*)&hA, (void*)&hB, (void*)&out, (void*)&bar};
    hipLaunchCooperativeKernel((const void*)lstm_seq, dim3(256), dim3(1024),
                               args, LDS_BYTES, stream);
}

// Round 17
// 1770.504 us; speedup vs baseline: 1.0157x; 1.0157x over previous
//
#include <hip/hip_runtime.h>

#define BATCH    1024
#define UNITS    1024
#define INSTEPS  64
#define OUTSTEPS 32
#define NF       4
#define NSTEPS   (INSTEPS + OUTSTEPS - 1)   // 95

typedef _Float16 half8 __attribute__((ext_vector_type(8)));
typedef float    f32x4 __attribute__((ext_vector_type(4)));

__device__ __forceinline__ float sigf(float x)  { return 1.0f / (1.0f + __expf(-x)); }
__device__ __forceinline__ float tanhf_(float x){ return 1.0f - 2.0f / (__expf(2.0f * x) + 1.0f); }

// 16-lane row sum via DPP row_shr (VALU pipe, no LDS ops). Result in lane 15
// of each 16-lane row (bound_ctrl=1 -> shifted-in lanes contribute 0).
__device__ __forceinline__ float dpp_rowsum16(float v) {
    int x;
    x = __builtin_amdgcn_update_dpp(0, __builtin_bit_cast(int, v), 0x111, 0xf, 0xf, true);
    v += __builtin_bit_cast(float, x);   // += row_shr:1
    x = __builtin_amdgcn_update_dpp(0, __builtin_bit_cast(int, v), 0x112, 0xf, 0xf, true);
    v += __builtin_bit_cast(float, x);   // += row_shr:2
    x = __builtin_amdgcn_update_dpp(0, __builtin_bit_cast(int, v), 0x114, 0xf, 0xf, true);
    v += __builtin_bit_cast(float, x);   // += row_shr:4
    x = __builtin_amdgcn_update_dpp(0, __builtin_bit_cast(int, v), 0x118, 0xf, 0xf, true);
    v += __builtin_bit_cast(float, x);   // += row_shr:8
    return v;
}

// One-time: U fp32 [1024 k][4096 n] -> Ut f16 [4096 n][1024 k] (transposed)
__global__ void u_transpose(const float* __restrict__ U, _Float16* __restrict__ Ut) {
    __shared__ _Float16 T[64][72];
    const int tid = threadIdx.x;
    const int bid = blockIdx.x;            // 1024 blocks = 16 (k) x 64 (n)
    const int k0 = (bid >> 6) << 6;
    const int n0 = (bid & 63) << 6;
    #pragma unroll
    for (int i = 0; i < 16; ++i) {
        int q = i * 256 + tid;
        int r = q >> 6, cc = q & 63;
        T[r][cc] = (_Float16)U[(size_t)(k0 + r) * 4096 + n0 + cc];
    }
    __syncthreads();
    #pragma unroll
    for (int i = 0; i < 16; ++i) {
        int q = i * 256 + tid;
        int nn = q >> 6, kk = q & 63;
        Ut[(size_t)(n0 + nn) * 1024 + k0 + kk] = T[kk][nn];
    }
}

// Persistent cooperative kernel, all 95 steps. 256 blocks (1/CU) x 1024 threads.
// FINAL (session optimum, R11/R15): K-split 16 waves = 8 row-tiles x 2
// K-halves, 4 waves/SIMD, band counter barrier + agent fence, decode folding
// (U' = U + Wd@W at p==64), transposed h layout [ut][row][16] + LDS-staged
// coalesced agent h-stores, DPP pred reduce after barrier-arrive, 3-round/
// 6-sync partial-z exchange (xb overlaid with hst), staging syncs only at
// p==0 / p==INSTEPS. R16's setprio reverted (null mean, 31ms tail outlier:
// prio-1 compute waves can starve prio-0 barrier pollers).
// Structural state: latency/sync-bound -- no pipe above ~30% duty; residual
// is the 95x serialized {5 syncs + 64-block LLC convergence + acquire fence
// + cold h refill} complex. Alternatives disqualified on HW: LLC-direct reads
// (R7, 6x FETCH), flag protocols (R12-R14, 3 correctness fails), extra TLP
// (R1), prefetch depth (R6), setprio (R16).
#define BS_BYTES  (16*64*64*2)                 // 131072
#define XS_BYTES  (256*4*4)                    // 4096
#define SH_OFF    (BS_BYTES + XS_BYTES)
#define SH_BYTES  (3*8*64*16)                  // 24576: xb[3][8][64] f32x4,
                                               // hst[256][18] f16 (9216B) overlaid
#define LDS_BYTES (SH_OFF + SH_BYTES)          // 159744 <= 163840

__global__ __launch_bounds__(1024, 4) void lstm_seq(
    const float* __restrict__ x, const float* __restrict__ W,
    const float* __restrict__ bias, const float* __restrict__ Wd,
    const float* __restrict__ bd, const _Float16* __restrict__ Ut,
    _Float16* hA, _Float16* hB, float* out, unsigned* bar)
{
    extern __shared__ __align__(16) char smem[];
    _Float16 (*Bs)[64][64] = (_Float16 (*)[64][64])smem;       // [16 chunks][64 n][64 k]
    float (*xs)[NF] = (float (*)[NF])(smem + BS_BYTES);        // [256][4]
    f32x4 (*xb)[8][64] = (f32x4 (*)[8][64])(smem + SH_OFF);    // [3][8][64]
    _Float16 (*hst)[18] = (_Float16 (*)[18])(smem + SH_OFF);   // overlaid (xb dead)

    const int tid  = threadIdx.x;
    const int bid  = blockIdx.x;
    const int band = bid & 3;
    const int m0   = band << 8;            // 256-row band, XCD-pair local
    const int u0   = (bid >> 2) << 4;      // 64 u-tiles of 16 units

    const int lane = tid & 63;
    const int wv   = tid >> 6;             // 0..15
    const int rt2  = wv & 7;               // row-tile: rows rt2*32..+31
    const int kh   = wv >> 3;              // K-half: 0 => K[0,512), 1 => K[512,1024)
    const int quad = lane >> 4;
    const int ln   = lane & 15;

    unsigned* cnt = bar + band * 64;       // per-band counter, 256B apart

    // staging geometry (init stage AND the p==64 U' restage) -- first 512 thr
    const int r_st = (tid >> 3) & 63;              // 0..63 (B-col within tile)
    const int ck   = tid & 7;                      // logical 16B chunk
    const int swz  = ((ck ^ (r_st & 7)) << 3);     // physical half-offset
    const int n_st = ((r_st >> 4) << 10) + u0 + (r_st & 15);   // global gate-col
    const _Float16* bsrc = Ut + (size_t)n_st * UNITS + ck * 8;

    // ---- stage B-tile (U) into LDS once, XOR-swizzled on 16B chunks ----
    if (tid < 512) {
        #pragma unroll
        for (int kc = 0; kc < 16; ++kc)
            *(float4*)&Bs[kc][r_st][swz] = *(const float4*)(bsrc + kc * 64);
    }

    // ---- hoisted weights ----
    float wt[4][4], bt[4], btp[4];
    #pragma unroll
    for (int g = 0; g < 4; ++g) {
        int col = (g << 10) + u0 + ln;
        bt[g] = bias[col];
        #pragma unroll
        for (int f = 0; f < 4; ++f) wt[g][f] = W[f * 4096 + col];
    }
    {   // decode bias b' = b + bd@W
        float bdr0 = bd[0], bdr1 = bd[1], bdr2 = bd[2], bdr3 = bd[3];
        #pragma unroll
        for (int g = 0; g < 4; ++g)
            btp[g] = bt[g] + bdr0*wt[g][0] + bdr1*wt[g][1] + bdr2*wt[g][2] + bdr3*wt[g][3];
    }
    const float* wdp = Wd + (size_t)(u0 + ln) * NF;
    float wd0 = wdp[0], wd1 = wdp[1], wd2 = wdp[2], wd3 = wdp[3];
    float bd0 = 0, bd1 = 0, bd2 = 0, bd3 = 0;
    if (u0 == 0) { bd0 = bd[0]; bd1 = bd[1]; bd2 = bd[2]; bd3 = bd[3]; }

    float cr[2][4] = {{0,0,0,0},{0,0,0,0}};   // c-state (kh=0 waves only used)
    float hnv[2][4];                          // h of this step (post-arrive pred)

    // swizzled B-frag read offsets (row&7 == ln&7 for all four row groups)
    const int swz0 = ((quad ^ (ln & 7)) << 3);   // k-sub 0
    const int swz1 = swz0 ^ 32;                  // k-sub 1 (chunk 4+quad)

    // A-load geometry in transposed h layout: addr(row, k) =
    //   (k>>4)*32768 + row*32 + (k&15)*2.  k = kh*512 + kcg*64 + quad*8 + j*32.
    const int row0 = m0 + rt2 * 32 + ln;
    const int aoff = ((quad >> 1) << 15) + row0 * 32 + ((quad & 1) << 4);

    // xt staging: 1024 threads cover 256 rows x 4 features exactly
    const int xr = tid >> 2, xf = tid & 3;
    float xp0 = x[(size_t)(m0 + xr) * (INSTEPS * NF) + xf];

    // coalesced h-store geometry (threads 0..511, wave-private hst rows)
    char* const hAc = (char*)hA;
    char* const hBc = (char*)hB;
    const size_t stoff = ((size_t)(u0 >> 4) << 15) + (size_t)(m0 + (tid >> 1)) * 32
                       + ((size_t)(tid & 1) << 4);

    __syncthreads();   // Bs ready

    for (int p = 0; p < NSTEPS; ++p) {
        if (p < INSTEPS) {                 // warmup: stage xt (ordering for the
            xs[xr][xf] = xp0;              //  epilogue comes from exchange syncs)
        } else if (p == INSTEPS && tid < 512) {
            // ---- re-stage Bs as U' = U + Wd@W (decode folding) ----
            float wc0 = W[n_st], wc1 = W[4096 + n_st],
                  wc2 = W[8192 + n_st], wc3 = W[12288 + n_st];
            #pragma unroll
            for (int kc = 0; kc < 16; ++kc) {
                int k0 = kc * 64 + ck * 8;
                half8 uv = *(const half8*)(bsrc + kc * 64);
                half8 tv;
                #pragma unroll
                for (int j = 0; j < 8; ++j) {
                    const float* wdr = Wd + (size_t)(k0 + j) * NF;
                    float corr = wdr[0]*wc0 + wdr[1]*wc1 + wdr[2]*wc2 + wdr[3]*wc3;
                    tv[j] = (_Float16)((float)uv[j] + corr);
                }
                *(half8*)&Bs[kc][r_st][swz] = tv;
            }
        }
        if (p == 0 || p == INSTEPS) __syncthreads();   // xs(p0)/Bs restage ready

        f32x4 acc[2][4] = {};

        if (p > 0) {
            const char* hb = ((p & 1) ? hAc : hBc) + aoff;   // written at step p-1
#define AL(kcg, j, rr) (*(const half8*)(hb + ((((kcg) << 2) + ((j) << 1)) << 15) + ((rr) << 9)))

            half8 ar[2][4];
            #pragma unroll
            for (int d = 0; d < 2; ++d) {              // depth-2 prefetch pipeline
                const int kcg = (kh << 3) + d;
                ar[d][0] = AL(kcg, 0, 0);
                ar[d][1] = AL(kcg, 1, 0);
                ar[d][2] = AL(kcg, 0, 1);
                ar[d][3] = AL(kcg, 1, 1);
            }

            #pragma unroll
            for (int kc = 0; kc < 8; ++kc) {           // my K-half: 8 chunks
                const int sl = kc & 1;
                half8 af0 = ar[sl][0], ag0 = ar[sl][1], af1 = ar[sl][2], ag1 = ar[sl][3];
                if (kc < 6) {
                    const int kcg = (kh << 3) + kc + 2;
                    ar[sl][0] = AL(kcg, 0, 0);
                    ar[sl][1] = AL(kcg, 1, 0);
                    ar[sl][2] = AL(kcg, 0, 1);
                    ar[sl][3] = AL(kcg, 1, 1);
                }
                const _Float16 (*B)[64] = Bs[(kh << 3) + kc];
                half8 bf0 = *(const half8*)&B[ln][swz0];
                half8 bf1 = *(const half8*)&B[16 + ln][swz0];
                half8 bf2 = *(const half8*)&B[32 + ln][swz0];
                half8 bf3 = *(const half8*)&B[48 + ln][swz0];
                acc[0][0] = __builtin_amdgcn_mfma_f32_16x16x32_f16(af0, bf0, acc[0][0], 0, 0, 0);
                acc[1][0] = __builtin_amdgcn_mfma_f32_16x16x32_f16(af1, bf0, acc[1][0], 0, 0, 0);
                acc[0][1] = __builtin_amdgcn_mfma_f32_16x16x32_f16(af0, bf1, acc[0][1], 0, 0, 0);
                acc[1][1] = __builtin_amdgcn_mfma_f32_16x16x32_f16(af1, bf1, acc[1][1], 0, 0, 0);
                acc[0][2] = __builtin_amdgcn_mfma_f32_16x16x32_f16(af0, bf2, acc[0][2], 0, 0, 0);
                acc[1][2] = __builtin_amdgcn_mfma_f32_16x16x32_f16(af1, bf2, acc[1][2], 0, 0, 0);
                acc[0][3] = __builtin_amdgcn_mfma_f32_16x16x32_f16(af0, bf3, acc[0][3], 0, 0, 0);
                acc[1][3] = __builtin_amdgcn_mfma_f32_16x16x32_f16(af1, bf3, acc[1][3], 0, 0, 0);
                half8 bg0 = *(const half8*)&B[ln][swz1];
                half8 bg1 = *(const half8*)&B[16 + ln][swz1];
                half8 bg2 = *(const half8*)&B[32 + ln][swz1];
                half8 bg3 = *(const half8*)&B[48 + ln][swz1];
                acc[0][0] = __builtin_amdgcn_mfma_f32_16x16x32_f16(ag0, bg0, acc[0][0], 0, 0, 0);
                acc[1][0] = __builtin_amdgcn_mfma_f32_16x16x32_f16(ag1, bg0, acc[1][0], 0, 0, 0);
                acc[0][1] = __builtin_amdgcn_mfma_f32_16x16x32_f16(ag0, bg1, acc[0][1], 0, 0, 0);
                acc[1][1] = __builtin_amdgcn_mfma_f32_16x16x32_f16(ag1, bg1, acc[1][1], 0, 0, 0);
                acc[0][2] = __builtin_amdgcn_mfma_f32_16x16x32_f16(ag0, bg2, acc[0][2], 0, 0, 0);
                acc[1][2] = __builtin_amdgcn_mfma_f32_16x16x32_f16(ag1, bg2, acc[1][2], 0, 0, 0);
                acc[0][3] = __builtin_amdgcn_mfma_f32_16x16x32_f16(ag0, bg3, acc[0][3], 0, 0, 0);
                acc[1][3] = __builtin_amdgcn_mfma_f32_16x16x32_f16(ag1, bg3, acc[1][3], 0, 0, 0);
            }
#undef AL

            // ---- partial-z exchange: 3 rounds (3,3,2 pairs), kh=1 writes ----
            #pragma unroll
            for (int rd = 0; rd < 3; ++rd) {
                const int base = rd * 3;
                const int cntw = (rd == 2) ? 2 : 3;
                const int slx  = rt2 - base;
                if (kh == 1 && slx >= 0 && slx < cntw) {
                    #pragma unroll
                    for (int j = 0; j < 8; ++j)
                        xb[slx][j][lane] = acc[j >> 2][j & 3];
                }
                __syncthreads();
                if (kh == 0 && slx >= 0 && slx < cntw) {
                    #pragma unroll
                    for (int j = 0; j < 8; ++j)
                        acc[j >> 2][j & 3] += xb[slx][j][lane];
                }
                __syncthreads();
            }
        }

        const int s_out = p - (INSTEPS - 1);

        if (kh == 0) {
            // ---- epilogue: gates, c/h update into wave-private LDS staging ----
            #pragma unroll
            for (int r = 0; r < 2; ++r) {
                #pragma unroll
                for (int i = 0; i < 4; ++i) {
                    int rl = rt2 * 32 + r * 16 + quad * 4 + i;  // C/D: row=quad*4+reg
                    float zi, zf, zg, zo;
                    if (p < INSTEPS) {
                        float x0 = xs[rl][0], x1 = xs[rl][1], x2 = xs[rl][2], x3 = xs[rl][3];
                        zi = acc[r][0][i] + bt[0] + x0*wt[0][0] + x1*wt[0][1] + x2*wt[0][2] + x3*wt[0][3];
                        zf = acc[r][1][i] + bt[1] + x0*wt[1][0] + x1*wt[1][1] + x2*wt[1][2] + x3*wt[1][3];
                        zg = acc[r][2][i] + bt[2] + x0*wt[2][0] + x1*wt[2][1] + x2*wt[2][2] + x3*wt[2][3];
                        zo = acc[r][3][i] + bt[3] + x0*wt[3][0] + x1*wt[3][1] + x2*wt[3][2] + x3*wt[3][3];
                    } else {                    // decode: x-term folded into U', b'
                        zi = acc[r][0][i] + btp[0];
                        zf = acc[r][1][i] + btp[1];
                        zg = acc[r][2][i] + btp[2];
                        zo = acc[r][3][i] + btp[3];
                    }
                    float cold = cr[r][i];
                    float si = sigf(zi), sf = sigf(zf), so = sigf(zo);
                    float cn = sf * cold + si * tanhf_(zg);
                    float hn = so * tanhf_(cn);
                    cr[r][i] = cn;
                    hnv[r][i] = hn;
                    hst[rl][ln] = (_Float16)hn;            // wave-private staging rows
                }
            }

            // ---- coalesced agent h-store (wave-private hst rows, tid<512) ----
            {
                char* hw = (p & 1) ? hBc : hAc;
                const unsigned long long* sp = (const unsigned long long*)
                    ((const char*)hst + (tid >> 1) * 36 + ((tid & 1) << 4));
                unsigned long long v0 = sp[0], v1 = sp[1];
                unsigned long long* dst = (unsigned long long*)(hw + stoff);
                __hip_atomic_store(dst,     v0, __ATOMIC_RELAXED, __HIP_MEMORY_SCOPE_AGENT);
                __hip_atomic_store(dst + 1, v1, __ATOMIC_RELAXED, __HIP_MEMORY_SCOPE_AGENT);
            }
        }

        const int pn = p + 1;

        // ---- drain h stores, arrive at band barrier ----
        __syncthreads();                               // vmcnt(0): h stores at LLC
        if (tid == 0)
            __hip_atomic_fetch_add(cnt, 1u, __ATOMIC_RELAXED, __HIP_MEMORY_SCOPE_AGENT);

        // ---- pred DPP reduce + out atomics AFTER arrive (overlap the poll) ----
        if (kh == 0 && s_out >= 0) {
            #pragma unroll
            for (int r = 0; r < 2; ++r) {
                #pragma unroll
                for (int i = 0; i < 4; ++i) {
                    float hn = hnv[r][i];
                    float p0 = dpp_rowsum16(hn * wd0);   // VALU-pipe reductions
                    float p1 = dpp_rowsum16(hn * wd1);
                    float p2 = dpp_rowsum16(hn * wd2);
                    float p3 = dpp_rowsum16(hn * wd3);
                    if (ln == 15) {                      // lane 15 holds row sum
                        int R = m0 + rt2 * 32 + r * 16 + quad * 4 + i;
                        float* op = out + (size_t)R * (OUTSTEPS * NF) + s_out * NF;
                        atomicAdd(op + 0, p0 + bd0);
                        atomicAdd(op + 1, p1 + bd1);
                        atomicAdd(op + 2, p2 + bd2);
                        atomicAdd(op + 3, p3 + bd3);
                    }
                }
            }
        }

        if (pn < INSTEPS) {                        // prefetch next xt (warmup only)
            xp0 = x[(size_t)(m0 + xr) * (INSTEPS * NF) + pn * NF + xf];
        }

        // ---- band-local barrier poll (64 blocks on XCD pair {band, band+4}) ----
        if (tid == 0) {
            const unsigned tgt = (unsigned)pn * 64u;
            while (__hip_atomic_load(cnt, __ATOMIC_RELAXED, __HIP_MEMORY_SCOPE_AGENT) < tgt)
                __builtin_amdgcn_s_sleep(1);
            __builtin_amdgcn_fence(__ATOMIC_ACQUIRE, "agent");   // L1/L2 inv
        }
        __syncthreads();                           // also drains out atomics
    }
}

extern "C" void kernel_launch(void* const* d_in, const int* in_sizes, int n_in,
                              void* d_out, int out_size, void* d_ws, size_t ws_size,
                              hipStream_t stream) {
    (void)in_sizes; (void)n_in; (void)ws_size;
    const float* x  = (const float*)d_in[0];
    const float* W  = (const float*)d_in[1];
    const float* U  = (const float*)d_in[2];
    const float* b  = (const float*)d_in[3];
    const float* Wd = (const float*)d_in[4];
    const float* bd = (const float*)d_in[5];
    float* out = (float*)d_out;

    char* ws = (char*)d_ws;
    _Float16* hA  = (_Float16*)ws;                    // 2 MB  h ping   [ut][row][16]
    _Float16* hB  = (_Float16*)(ws + (2 << 20));      // 2 MB  h pong
    _Float16* Ut  = (_Float16*)(ws + (4 << 20));      // 8 MB  U^T f16
    unsigned* bar = (unsigned*)(ws + (12 << 20));     // 4 KB  barrier state

    hipMemsetAsync(bar, 0, 4096, stream);                               // band counters
    hipMemsetAsync(d_out, 0, (size_t)out_size * sizeof(float), stream); // preds accumulate
    u_transpose<<<1024, 256, 0, stream>>>(U, Ut);

    hipFuncSetAttribute((const void*)lstm_seq,
                        hipFuncAttributeMaxDynamicSharedMemorySize, LDS_BYTES);

    void* args[] = {(void*)&x, (void*)&W, (void*)&b, (void*)&Wd, (void*)&bd,
                    (void*)&Ut, (void*)&hA, (void*)&hB, (void*)&out, (void*)&bar};
    hipLaunchCooperativeKernel((const void*)lstm_seq, dim3(256), dim3(1024),
                               args, LDS_BYTES, stream);
}